// Round 1
// baseline (108.805 us; speedup 1.0000x reference)
//
#include <hip/hip_runtime.h>
#include <hip/hip_bf16.h>

// Problem constants (from reference)
#define NUM_NEURONS 32768
#define INPUT_SIZE  8192
#define BATCH       512

// ---------------------------------------------------------------------------
// Kernel A: per-neuron softmax over 16 gate weights -> 4 affine coefficients.
// Every logic op is affine in {1, a, b, ab}:
//   k : (c0, ca, cb, cab)
//   0:(0,0,0,0) 1:(0,0,0,1) 2:(0,1,0,-1) 3:(0,1,0,0) 4:(0,0,1,-1) 5:(0,0,1,0)
//   6:(0,1,1,-2) 7:(0,1,1,-1) 8:(1,-1,-1,1) 9:(1,-1,-1,2) 10:(1,0,-1,0)
//   11:(1,0,-1,1) 12:(1,-1,0,0) 13:(1,-1,0,1) 14:(1,0,0,-1) 15:(1,0,0,0)
// ---------------------------------------------------------------------------
__global__ __launch_bounds__(256) void logic_coeff_kernel(
    const float* __restrict__ gw, float4* __restrict__ coeffs)
{
    const int n = blockIdx.x * 256 + threadIdx.x;
    if (n >= NUM_NEURONS) return;
    const float* g = gw + (size_t)n * 16;

    float w[16];
#pragma unroll
    for (int i = 0; i < 16; i += 4) {
        float4 v = *reinterpret_cast<const float4*>(g + i);
        w[i+0] = v.x; w[i+1] = v.y; w[i+2] = v.z; w[i+3] = v.w;
    }
    float m = w[0];
#pragma unroll
    for (int i = 1; i < 16; ++i) m = fmaxf(m, w[i]);
    float s = 0.f;
#pragma unroll
    for (int i = 0; i < 16; ++i) { w[i] = expf(w[i] - m); s += w[i]; }
    const float inv = 1.0f / s;

    const float C0  = (w[8] + w[9] + w[10] + w[11] + w[12] + w[13] + w[14] + w[15]) * inv;
    const float Ca  = (w[2] + w[3] + w[6] + w[7] - w[8] - w[9] - w[12] - w[13]) * inv;
    const float Cb  = (w[4] + w[5] + w[6] + w[7] - w[8] - w[9] - w[10] - w[11]) * inv;
    const float Cab = (w[1] - w[2] - w[4] - 2.f*w[6] - w[7]
                       + w[8] + 2.f*w[9] + w[11] + w[13] - w[14]) * inv;

    coeffs[n] = make_float4(C0, Ca, Cb, Cab);
}

// ---------------------------------------------------------------------------
// Kernel B: out[r,n] = C0 + Ca*a + Cb*b + Cab*a*b  with a=x[r,i0], b=x[r,i1].
// Block: 256 threads, owns CHUNK=2048 neurons (coeff+idx held in registers),
// loops over ROWS_PER_BLOCK=4 batch rows staging each 32 KiB x-row in LDS.
// ---------------------------------------------------------------------------
constexpr int CHUNK = 2048;            // neurons per block
constexpr int NPT   = CHUNK / 256;     // 8 neurons per thread
constexpr int ROWS_PER_BLOCK = 4;

__global__ __launch_bounds__(256) void logic_main_kernel(
    const float*  __restrict__ x,
    const float4* __restrict__ coeffs,
    const int2*   __restrict__ idx,
    float*        __restrict__ out)
{
    __shared__ float sx[INPUT_SIZE];   // 32 KiB: one batch row of x

    const int tid    = threadIdx.x;
    const int chunk0 = blockIdx.x * CHUNK;
    const int row0   = blockIdx.y * ROWS_PER_BLOCK;

    // Load this thread's neurons' coefficients and indices once (registers).
    float4 c[NPT];
    int2   id[NPT];
#pragma unroll
    for (int i = 0; i < NPT; ++i) {
        const int n = chunk0 + i * 256 + tid;
        c[i]  = coeffs[n];
        id[i] = idx[n];
    }

    for (int r = 0; r < ROWS_PER_BLOCK; ++r) {
        const int row = row0 + r;
        if (r) __syncthreads();        // previous iteration's gathers done

        // Stage x[row, :] into LDS, coalesced float4 loads.
        const float4* xrow = reinterpret_cast<const float4*>(x + (size_t)row * INPUT_SIZE);
        float4* s4 = reinterpret_cast<float4*>(sx);
#pragma unroll
        for (int i = 0; i < INPUT_SIZE / 4 / 256; ++i)   // 8 iterations
            s4[i * 256 + tid] = xrow[i * 256 + tid];
        __syncthreads();

        float* o = out + (size_t)row * NUM_NEURONS + chunk0 + tid;
#pragma unroll
        for (int i = 0; i < NPT; ++i) {
            const float a = sx[id[i].x];
            const float b = sx[id[i].y];
            // C0 + Ca*a + Cb*b + Cab*(a*b)
            o[i * 256] = c[i].x + a * (c[i].y + c[i].w * b) + c[i].z * b;
        }
    }
}

extern "C" void kernel_launch(void* const* d_in, const int* in_sizes, int n_in,
                              void* d_out, int out_size, void* d_ws, size_t ws_size,
                              hipStream_t stream)
{
    const float* x   = (const float*)d_in[0];   // (512, 8192) f32
    const float* gw  = (const float*)d_in[1];   // (32768, 16) f32
    const int2*  idx = (const int2*)d_in[2];    // (32768, 2) i32
    float* out = (float*)d_out;                 // (512, 32768) f32

    float4* coeffs = (float4*)d_ws;             // 32768 * 16 B = 512 KiB scratch

    // Kernel A: 32768 neurons, 256 threads/block
    logic_coeff_kernel<<<NUM_NEURONS / 256, 256, 0, stream>>>(gw, coeffs);

    // Kernel B: grid (neuron chunks, row groups)
    dim3 grid(NUM_NEURONS / CHUNK, BATCH / ROWS_PER_BLOCK);
    logic_main_kernel<<<grid, 256, 0, stream>>>(x, coeffs, idx, out);
}